// Round 4
// baseline (1197.155 us; speedup 1.0000x reference)
//
#include <hip/hip_runtime.h>

// Problem sizes
// B=8 M=4 T=2048 E=768 P=256 K=64 V=64 H=128 NEXP=16 COMB=384 HID=192
// tokens NT = 65536, sequences NSEQ = 32
// Round 4: hoist x-projection out of the GRU serial loop — per-chunk burst
// computes next chunk's xq[3][32][128] into LDS using all 512 lanes evenly
// (2.25 FMA/step amortized vs 9 FMA/step on the critical stream).

typedef unsigned short u16;
typedef float f32x4 __attribute__((ext_vector_type(4)));
typedef short s16x8 __attribute__((ext_vector_type(8)));
typedef unsigned u32x2 __attribute__((ext_vector_type(2)));

#define DI static __device__ __forceinline__

#define L2E  1.44269504088896340736f
#define L2E2 2.88539008177792681472f

DI u16 f2b(float f) {  // fp32 -> bf16 RNE (prep-time use)
  unsigned u = __builtin_bit_cast(unsigned, f);
  u += 0x7fffu + ((u >> 16) & 1u);
  return (u16)(u >> 16);
}
DI u16 f2b_cvt(float f) {  // 1-op hardware convert (hot loop)
  unsigned r;
  asm("v_cvt_pk_bf16_f32 %0, %1, %2" : "=v"(r) : "v"(f), "v"(f));
  return (u16)r;
}
DI float rcp_fast(float x) { return __builtin_amdgcn_rcpf(x); }
DI float exp2_fast(float x) { return __builtin_exp2f(x); }  // v_exp_f32
DI f32x4 mfma16(s16x8 a, s16x8 b, f32x4 c) {
  return __builtin_amdgcn_mfma_f32_16x16x32_bf16(a, b, c, 0, 0, 0);
}

// ---- workspace layout (bytes) ----
#define OFF_COMB   0ull            // u16 [65536][384]  (proc | rus)      50331648
#define OFF_URS    50331648ull     // f32 [32][2048][4] {U, rbar, sbar, 0} 1048576
#define OFF_TPWB   51380736ull     // u16 [256][768]                        393216
#define OFF_WHHB   51773952ull     // u16 [384][128]  (exp2-prescaled)       98304
#define OFF_W1B    51872256ull     // u16 [192][384]                        147456
#define OFF_W2B    52019712ull     // u16 [16][192]                           6144
#define OFF_WABC   52025856ull     // f32 wA[256] wB[256] wC[256]             3072
#define OFF_CABC   52028928ull     // f32 cA cB cC pad                          16
#define OFF_GX     52028944ull     // f32 gxu[384] gxr[384] gxs[384] gxc[384] 6144
// gx rows j<256 (r,z): scaled by -log2e (includes folded b_hh).
// gx rows j>=256 (n): scaled by +2*log2e. whhb rows likewise prescaled.

// =====================================================================
// K0: derived weights + bf16 conversions (with exp2 prescale)
// =====================================================================
__global__ __launch_bounds__(512) void k_prep(
    const float* __restrict__ qw, const float* __restrict__ qb,
    const float* __restrict__ kw, const float* __restrict__ kb,
    const float* __restrict__ vw, const float* __restrict__ vb,
    const float* __restrict__ wih, const float* __restrict__ bih,
    const float* __restrict__ bhh,
    const float* __restrict__ tpw, const float* __restrict__ whh,
    const float* __restrict__ w1, const float* __restrict__ w2,
    u16* __restrict__ tpwb, u16* __restrict__ whhb,
    u16* __restrict__ w1b, u16* __restrict__ w2b,
    float* __restrict__ wabc, float* __restrict__ cabc, float* __restrict__ gx) {
  const int tid = threadIdx.x, bid = blockIdx.x;
  if (bid == 0 && tid < 256) {
    int p = tid;
    float a = 0.f, b = 0.f, c = 0.f;
    for (int j = 0; j < 64; j++) {
      float q = qw[j * 256 + p];
      a += q * kw[2 * j]; b += q * kw[2 * j + 1]; c += q * kb[j];
    }
    wabc[p] = a; wabc[256 + p] = b; wabc[512 + p] = c;
    if (p == 0) {
      float ca = 0.f, cb = 0.f, cc = 0.f;
      for (int j = 0; j < 64; j++) {
        ca += qb[j] * kw[2 * j]; cb += qb[j] * kw[2 * j + 1]; cc += qb[j] * kb[j];
      }
      cabc[0] = ca; cabc[1] = cb; cabc[2] = cc; cabc[3] = 0.f;
    }
  }
  if (bid == 1 && tid < 384) {
    int j = tid;
    float r = 0.f, s = 0.f, c0 = 0.f;
    for (int v = 0; v < 64; v++) {
      float w = wih[j * 65 + 1 + v];
      r += w * vw[2 * v]; s += w * vw[2 * v + 1]; c0 += w * vb[v];
    }
    float xc = c0 + bih[j] + (j < 256 ? bhh[j] : 0.f);
    float sc = (j < 256) ? -L2E : L2E2;
    gx[j] = wih[j * 65] * sc; gx[384 + j] = r * sc;
    gx[768 + j] = s * sc;     gx[1152 + j] = xc * sc;
  }
  const int n1 = 768 * 256, n2 = 384 * 128, n3 = 192 * 384, n4 = 16 * 192;
  const int total = n1 + n2 + n3 + n4;
  for (int i = bid * blockDim.x + tid; i < total; i += gridDim.x * blockDim.x) {
    if (i < n1) tpwb[i] = f2b(tpw[i]);
    else if (i < n1 + n2) {
      int loc = i - n1;                        // row = loc>>7 in [0,384)
      float sc = (loc < 256 * 128) ? L2E : L2E2;
      whhb[loc] = f2b(whh[loc] * sc);
    }
    else if (i < n1 + n2 + n3) w1b[i - n1 - n2] = f2b(w1[i - n1 - n2]);
    else w2b[i - n1 - n2 - n3] = f2b(w2[i - n1 - n2 - n3]);
  }
}

// =====================================================================
// K1: processed = relu(TE @ tp_w.T + tp_b)  -> comb[:, 0:256] (bf16)
// =====================================================================
__global__ __launch_bounds__(512, 1) void k_gemm1(
    const float* __restrict__ te, const float* __restrict__ tpb,
    const u16* __restrict__ tpwb, u16* __restrict__ comb) {
  __shared__ u16 Als[128 * 64];
  __shared__ u16 Bls[256 * 64];
  const int tid = threadIdx.x;
  const int lane = tid & 63, w = tid >> 6;
  const int c = lane & 15, g4 = lane >> 4;
  const int wm = w >> 2, wn = w & 3;
  const long row0 = (long)blockIdx.x * 128;

  f32x4 acc[4][4];
  #pragma unroll
  for (int i = 0; i < 4; i++)
    #pragma unroll
    for (int j = 0; j < 4; j++) acc[i][j] = (f32x4)(0.f);

  for (int kk = 0; kk < 12; kk++) {
    #pragma unroll
    for (int ii = 0; ii < 2; ii++) {
      int idx = tid + 512 * ii;
      int row = idx >> 3, kb = idx & 7;
      const float* g = te + (row0 + row) * 768 + kk * 64 + kb * 8;
      f32x4 p0 = *(const f32x4*)g;
      f32x4 p1 = *(const f32x4*)(g + 4);
      s16x8 v;
      v[0] = f2b(p0[0]); v[1] = f2b(p0[1]); v[2] = f2b(p0[2]); v[3] = f2b(p0[3]);
      v[4] = f2b(p1[0]); v[5] = f2b(p1[1]); v[6] = f2b(p1[2]); v[7] = f2b(p1[3]);
      *(s16x8*)&Als[row * 64 + ((kb ^ (row & 7)) << 3)] = v;
    }
    #pragma unroll
    for (int ii = 0; ii < 4; ii++) {
      int idx = tid + 512 * ii;
      int n = idx >> 3, kb = idx & 7;
      s16x8 v = *(const s16x8*)(tpwb + n * 768 + kk * 64 + kb * 8);
      *(s16x8*)&Bls[n * 64 + ((kb ^ (n & 7)) << 3)] = v;
    }
    __syncthreads();
    #pragma unroll
    for (int kt = 0; kt < 2; kt++) {
      s16x8 af[4], bf[4];
      #pragma unroll
      for (int mt = 0; mt < 4; mt++) {
        int row = wm * 64 + mt * 16 + c;
        af[mt] = *(const s16x8*)&Als[row * 64 + (((kt * 4 + g4) ^ (row & 7)) << 3)];
      }
      #pragma unroll
      for (int nt = 0; nt < 4; nt++) {
        int n = wn * 64 + nt * 16 + c;
        bf[nt] = *(const s16x8*)&Bls[n * 64 + (((kt * 4 + g4) ^ (n & 7)) << 3)];
      }
      #pragma unroll
      for (int mt = 0; mt < 4; mt++)
        #pragma unroll
        for (int nt = 0; nt < 4; nt++)
          acc[mt][nt] = mfma16(af[mt], bf[nt], acc[mt][nt]);
    }
    __syncthreads();
  }
  #pragma unroll
  for (int nt = 0; nt < 4; nt++) {
    int col = wn * 64 + nt * 16 + c;
    float bias = tpb[col];
    #pragma unroll
    for (int mt = 0; mt < 4; mt++)
      #pragma unroll
      for (int r = 0; r < 4; r++) {
        long row = row0 + wm * 64 + mt * 16 + g4 * 4 + r;
        float v = fmaxf(acc[mt][nt][r] + bias, 0.f);
        comb[row * 384 + col] = f2b(v);
      }
  }
}

// =====================================================================
// K2: collapsed attention. Per token: 3 dots of 256, softmax over 3
// "others", emit (U, rbar, sbar). One wave per token.
// =====================================================================
__global__ __launch_bounds__(256) void k_attn(
    const u16* __restrict__ comb, const float* __restrict__ U,
    const float* __restrict__ R, const float* __restrict__ S,
    const float* __restrict__ wabc, const float* __restrict__ cabc,
    float* __restrict__ urs) {
  const int lane = threadIdx.x & 63;
  const long token = (long)blockIdx.x * 4 + (threadIdx.x >> 6);
  const int t = (int)(token & 2047);
  const int seq = (int)(token >> 11);
  const int m = seq & 3;

  u32x2 pv = *(const u32x2*)(comb + token * 384 + lane * 4);
  float p0 = __builtin_bit_cast(float, pv[0] << 16);
  float p1 = __builtin_bit_cast(float, pv[0] & 0xffff0000u);
  float p2 = __builtin_bit_cast(float, pv[1] << 16);
  float p3 = __builtin_bit_cast(float, pv[1] & 0xffff0000u);
  f32x4 wa = *(const f32x4*)(wabc + lane * 4);
  f32x4 wb = *(const f32x4*)(wabc + 256 + lane * 4);
  f32x4 wc = *(const f32x4*)(wabc + 512 + lane * 4);
  float a = p0 * wa[0] + p1 * wa[1] + p2 * wa[2] + p3 * wa[3];
  float b = p0 * wb[0] + p1 * wb[1] + p2 * wb[2] + p3 * wb[3];
  float cd = p0 * wc[0] + p1 * wc[1] + p2 * wc[2] + p3 * wc[3];
  #pragma unroll
  for (int off = 32; off; off >>= 1) {
    a += __shfl_xor(a, off); b += __shfl_xor(b, off); cd += __shfl_xor(cd, off);
  }
  a += cabc[0]; b += cabc[1]; cd += cabc[2];

  float rv[3], sv[3], sc[3];
  #pragma unroll
  for (int n = 0; n < 3; n++) {
    int o = n + (n >= m ? 1 : 0);
    long idx = ((long)seq * 4 + o) * 2048 + t;
    rv[n] = R[idx]; sv[n] = S[idx];
    sc[n] = (a * rv[n] + b * sv[n] + cd) * 0.125f;
  }
  float mx = fmaxf(sc[0], fmaxf(sc[1], sc[2]));
  float e0 = __expf(sc[0] - mx), e1 = __expf(sc[1] - mx), e2 = __expf(sc[2] - mx);
  float inv = rcp_fast(e0 + e1 + e2);
  float rb = (e0 * rv[0] + e1 * rv[1] + e2 * rv[2]) * inv;
  float sb = (e0 * sv[0] + e1 * sv[1] + e2 * sv[2]) * inv;
  if (lane == 0) {
    f32x4 v; v[0] = U[token]; v[1] = rb; v[2] = sb; v[3] = 0.f;
    *(f32x4*)(urs + ((long)seq * 2048 + t) * 4) = v;
  }
}

// =====================================================================
// K3: GRU scan. 1 block per sequence (32 blocks), 8 waves (512 thr).
// Hot loop per wave-step: 4 af b128 reads + 3 xq b32 reads, 12 MFMA,
// ~20 VALU (6 trans), masked h stores, 1 barrier. x-projection hoisted:
// per chunk a burst computes the NEXT chunk's xq[3][32][128] into LDS,
// work spread over all 512 lanes (lane (w,g4,c): 8 steps x 3 gates of
// its own column j) -> 2.25 FMA/step amortized vs 9 FMA/step inline.
// Buffer parities: chunk c reads xq buf c&1; burst during chunk c writes
// (c+1)&1, whose last reader (chunk c-1 step 31) is barrier-separated.
// =====================================================================
__global__ __launch_bounds__(512, 1) void k_gru(
    const u16* __restrict__ whhb, const float* __restrict__ bhh,
    const float* __restrict__ gx, const float* __restrict__ urs,
    u16* __restrict__ comb) {
  __shared__ u16 hbuf[2][128];          //  0.5 KB
  __shared__ u16 hist[2][32][128];      // 16 KB history chunks
  __shared__ float ulds[2048][4];       // 32 KB urs slice for this seq
  __shared__ float xqlds[2][3][32][128];// 96 KB x-projection dbuf
  const int tid = threadIdx.x;
  const int lane = tid & 63, w = tid >> 6;   // w in 0..7
  const int c = lane & 15, g4 = lane >> 4;
  const int seq = blockIdx.x;

  // one-time bulk load of this sequence's urs slice (contiguous 32 KB)
  for (int i = tid; i < 2048; i += 512)
    *(f32x4*)&ulds[i][0] = *(const f32x4*)(urs + ((long)seq * 2048 + i) * 4);

  const int j = w * 16 + c;                  // this lane's H column (0..127)
  s16x8 bfr[3][4];
  #pragma unroll
  for (int g = 0; g < 3; g++) {
    int n = g * 128 + j;
    #pragma unroll
    for (int kt = 0; kt < 4; kt++)
      bfr[g][kt] = *(const s16x8*)(whhb + n * 128 + kt * 32 + g4 * 8);
  }
  float gxv[3][4];
  #pragma unroll
  for (int g = 0; g < 3; g++) {
    int jj = g * 128 + j;
    gxv[g][0] = gx[jj];        gxv[g][1] = gx[384 + jj];
    gxv[g][2] = gx[768 + jj];  gxv[g][3] = gx[1152 + jj];
  }
  const float bhn = bhh[256 + j] * L2E2;     // scaled n-gate recurrent bias
  const f32x4 nseed = (f32x4)(bhn);          // MFMA C-seed

  if (tid < 128) { hbuf[0][tid] = 0; hbuf[1][tid] = 0; }
  __syncthreads();  // ulds + hbuf visible (burst reads ulds cross-thread)

  // prologue: xq burst for chunk 0 into buf 0
  {
    float* xb = &xqlds[0][0][0][0];
    #pragma unroll
    for (int i = 0; i < 8; i++) {
      int sp = g4 * 8 + i;
      f32x4 u = *(const f32x4*)&ulds[sp][0];
      #pragma unroll
      for (int g = 0; g < 3; g++)
        xb[(g * 32 + sp) * 128 + j] =
            gxv[g][3] + u[0] * gxv[g][0] + u[1] * gxv[g][1] + u[2] * gxv[g][2];
    }
  }
  float hprev = 0.f;
  __syncthreads();  // xq buf0 visible

  u16* rbase = comb + (long)seq * 2048 * 384 + 256;
  for (int chunk = 0; chunk < 64; chunk++) {
    // burst: compute next chunk's xq into buf (chunk+1)&1
    if (chunk < 63) {
      float* xb = &xqlds[(chunk + 1) & 1][0][0][0];
      const float* uc = &ulds[(chunk + 1) * 32][0];
      #pragma unroll
      for (int i = 0; i < 8; i++) {
        int sp = g4 * 8 + i;
        f32x4 u = *(const f32x4*)(uc + sp * 4);
        #pragma unroll
        for (int g = 0; g < 3; g++)
          xb[(g * 32 + sp) * 128 + j] =
              gxv[g][3] + u[0] * gxv[g][0] + u[1] * gxv[g][1] + u[2] * gxv[g][2];
      }
    }
    const float* xc = &xqlds[chunk & 1][0][0][0] + j;
    u16* hw = &hist[chunk & 1][0][j];
    #pragma unroll 8
    for (int s = 0; s < 32; s++) {
      s16x8 af[4];
      #pragma unroll
      for (int kt = 0; kt < 4; kt++)
        af[kt] = *(const s16x8*)&hbuf[s & 1][kt * 32 + g4 * 8];
      // 6 independent depth-2 MFMA chains (12 MFMAs/wave); n-chain C-seeded
      f32x4 aA[3], aB[3];
      #pragma unroll
      for (int g = 0; g < 3; g++) {
        f32x4 x0 = (f32x4)(0.f);
        f32x4 x1 = (g == 2) ? nseed : (f32x4)(0.f);
        x0 = mfma16(af[0], bfr[g][0], x0);
        x1 = mfma16(af[2], bfr[g][2], x1);
        x0 = mfma16(af[1], bfr[g][1], x0);
        x1 = mfma16(af[3], bfr[g][3], x1);
        aA[g] = x0; aB[g] = x1;
      }
      float xq0 = xc[s * 128];
      float xq1 = xc[(32 + s) * 128];
      float xq2 = xc[(64 + s) * 128];
      float hr2 = aA[0][0] + aB[0][0];
      float hz2 = aA[1][0] + aB[1][0];
      float hn2 = aA[2][0] + aB[2][0];       // includes scaled b_hh_n via seed
      float r = rcp_fast(1.f + exp2_fast(xq0 - hr2));
      float z = rcp_fast(1.f + exp2_fast(xq1 - hz2));
      float e = exp2_fast(xq2 + r * hn2);
      float n = __builtin_fmaf(-2.f, rcp_fast(e + 1.f), 1.f);
      float h = z * (hprev - n) + n;
      hprev = h;
      u16 hb = f2b_cvt(h);
      if (g4 == 0) {                         // conflict-free masked stores
        hbuf[(s + 1) & 1][j] = hb;
        hw[s * 128] = hb;
      }
      __syncthreads();
    }
    // flush chunk history: 32 rows x 256 B, coalesced 16 B stores
    const int t0 = chunk * 32;
    {
      int row = tid >> 4, part = tid & 15;
      s16x8 v = *(const s16x8*)&hist[chunk & 1][row][part * 8];
      *(s16x8*)(rbase + (long)(t0 + row) * 384 + part * 8) = v;
    }
  }
}

// =====================================================================
// K4: fused MLP: hid = relu(comb @ w1.T + b1) (bf16 via LDS), then
// logits = hid @ w2.T + b2 (fp32 out). 128 rows per block.
// =====================================================================
__global__ __launch_bounds__(512, 1) void k_mlp(
    const u16* __restrict__ comb, const u16* __restrict__ w1b,
    const float* __restrict__ b1, const u16* __restrict__ w2b,
    const float* __restrict__ b2, float* __restrict__ out) {
  __shared__ u16 smem[40960];  // 80 KB
  u16* Als = smem;             // 128x128
  u16* Bls = smem + 16384;     // 192x128
  u16* Hls = smem;             // 128x192 (reuse after barrier)
  const int tid = threadIdx.x;
  const int lane = tid & 63, w = tid >> 6;
  const int c = lane & 15, g4 = lane >> 4;
  const int wm = w >> 2, wn = w & 3;
  const long row0 = (long)blockIdx.x * 128;

  s16x8 w2f[6];
  #pragma unroll
  for (int kt = 0; kt < 6; kt++)
    w2f[kt] = *(const s16x8*)(w2b + c * 192 + kt * 32 + g4 * 8);
  const float b2v = b2[c];

  f32x4 acc[4][3];
  #pragma unroll
  for (int i = 0; i < 4; i++)
    #pragma unroll
    for (int j = 0; j < 3; j++) acc[i][j] = (f32x4)(0.f);

  for (int kc = 0; kc < 3; kc++) {
    #pragma unroll
    for (int ii = 0; ii < 4; ii++) {
      int idx = tid + 512 * ii;
      int row = idx >> 4, kb = idx & 15;
      s16x8 v = *(const s16x8*)(comb + (row0 + row) * 384 + kc * 128 + kb * 8);
      *(s16x8*)&Als[row * 128 + ((kb ^ (row & 7)) << 3)] = v;
    }
    #pragma unroll
    for (int ii = 0; ii < 6; ii++) {
      int idx = tid + 512 * ii;
      int n = idx >> 4, kb = idx & 15;
      s16x8 v = *(const s16x8*)(w1b + n * 384 + kc * 128 + kb * 8);
      *(s16x8*)&Bls[n * 128 + ((kb ^ (n & 7)) << 3)] = v;
    }
    __syncthreads();
    #pragma unroll
    for (int kt = 0; kt < 4; kt++) {
      s16x8 af[4], bf[3];
      #pragma unroll
      for (int mt = 0; mt < 4; mt++) {
        int row = wm * 64 + mt * 16 + c;
        af[mt] = *(const s16x8*)&Als[row * 128 + (((kt * 4 + g4) ^ (row & 7)) << 3)];
      }
      #pragma unroll
      for (int nt = 0; nt < 3; nt++) {
        int n = wn * 48 + nt * 16 + c;
        bf[nt] = *(const s16x8*)&Bls[n * 128 + (((kt * 4 + g4) ^ (n & 7)) << 3)];
      }
      #pragma unroll
      for (int mt = 0; mt < 4; mt++)
        #pragma unroll
        for (int nt = 0; nt < 3; nt++)
          acc[mt][nt] = mfma16(af[mt], bf[nt], acc[mt][nt]);
    }
    __syncthreads();
  }
  #pragma unroll
  for (int nt = 0; nt < 3; nt++) {
    int col = wn * 48 + nt * 16 + c;
    float bias = b1[col];
    int cb = col >> 3, cl = col & 7;
    #pragma unroll
    for (int mt = 0; mt < 4; mt++)
      #pragma unroll
      for (int r = 0; r < 4; r++) {
        int row = wm * 64 + mt * 16 + g4 * 4 + r;
        float v = fmaxf(acc[mt][nt][r] + bias, 0.f);
        Hls[row * 192 + ((cb ^ (row & 7)) << 3) + cl] = f2b(v);
      }
  }
  __syncthreads();
  f32x4 a2 = (f32x4)(0.f);
  const int row = w * 16 + c, r7 = row & 7;
  #pragma unroll
  for (int kt = 0; kt < 6; kt++) {
    s16x8 af = *(const s16x8*)&Hls[row * 192 + (((kt * 4 + g4) ^ r7) << 3)];
    a2 = mfma16(af, w2f[kt], a2);
  }
  #pragma unroll
  for (int r = 0; r < 4; r++) {
    long grow = row0 + w * 16 + g4 * 4 + r;
    out[grow * 16 + c] = a2[r] + b2v;
  }
}

// =====================================================================
extern "C" void kernel_launch(void* const* d_in, const int* in_sizes, int n_in,
                              void* d_out, int out_size, void* d_ws, size_t ws_size,
                              hipStream_t stream) {
  (void)in_sizes; (void)n_in; (void)out_size; (void)ws_size;
  const float* te  = (const float*)d_in[0];
  const float* U   = (const float*)d_in[1];
  const float* R   = (const float*)d_in[2];
  const float* S   = (const float*)d_in[3];
  const float* tpw = (const float*)d_in[4];
  const float* tpb = (const float*)d_in[5];
  const float* qw  = (const float*)d_in[6];
  const float* qb  = (const float*)d_in[7];
  const float* kw  = (const float*)d_in[8];
  const float* kb  = (const float*)d_in[9];
  const float* vw  = (const float*)d_in[10];
  const float* vb  = (const float*)d_in[11];
  const float* wih = (const float*)d_in[12];
  const float* whh = (const float*)d_in[13];
  const float* bih = (const float*)d_in[14];
  const float* bhh = (const float*)d_in[15];
  const float* w1  = (const float*)d_in[16];
  const float* b1  = (const float*)d_in[17];
  const float* w2  = (const float*)d_in[18];
  const float* b2  = (const float*)d_in[19];

  char* ws = (char*)d_ws;
  u16*   comb = (u16*)(ws + OFF_COMB);
  float* urs  = (float*)(ws + OFF_URS);
  u16*   tpwb = (u16*)(ws + OFF_TPWB);
  u16*   whhb = (u16*)(ws + OFF_WHHB);
  u16*   w1b  = (u16*)(ws + OFF_W1B);
  u16*   w2b  = (u16*)(ws + OFF_W2B);
  float* wabc = (float*)(ws + OFF_WABC);
  float* cabc = (float*)(ws + OFF_CABC);
  float* gx   = (float*)(ws + OFF_GX);
  float* out  = (float*)d_out;

  hipLaunchKernelGGL(k_prep, dim3(32), dim3(512), 0, stream,
                     qw, qb, kw, kb, vw, vb, wih, bih, bhh, tpw, whh, w1, w2,
                     tpwb, whhb, w1b, w2b, wabc, cabc, gx);
  hipLaunchKernelGGL(k_gemm1, dim3(512), dim3(512), 0, stream, te, tpb, tpwb, comb);
  hipLaunchKernelGGL(k_attn, dim3(16384), dim3(256), 0, stream, comb, U, R, S, wabc, cabc, urs);
  hipLaunchKernelGGL(k_gru, dim3(32), dim3(512), 0, stream, whhb, bhh, gx, urs, comb);
  hipLaunchKernelGGL(k_mlp, dim3(512), dim3(512), 0, stream, comb, w1b, b1, w2b, b2, out);
}